// Round 9
// baseline (26054.672 us; speedup 1.0000x reference)
//
#include <hip/hip_runtime.h>
#include <hip/hip_bf16.h>

#define S_LEN 4096
#define EDIM  300
#define HDIM  512
#define G4    2048
#define NTAG  5
#define NEGV  -10000.0f
#define START_TAG 3
#define STOP_TAG  4
#define L2E 1.4426950408889634f
#define LN2 0.6931471805599453f
#define POIS_U 0x7F7F7F7Fu

typedef __attribute__((ext_vector_type(4))) float f32x4;
typedef __attribute__((ext_vector_type(4))) unsigned int u32x4;

// ---------- workspace layout (bytes) — R2 layout ----------
static constexpr size_t OFF_XP    = 0;                                   // bf16 [2][S][2048]
static constexpr size_t XP_BYTES  = (size_t)2 * S_LEN * G4 * 2;
static constexpr size_t OFF_HBS   = OFF_XP + XP_BYTES;                   // f32 [2][S][512] poison-polled h history
static constexpr size_t HBS_BYTES = (size_t)2 * S_LEN * HDIM * 4;
static constexpr size_t OFF_FEATS = OFF_HBS + HBS_BYTES;                 // f32 [S][5]
static constexpr size_t OFF_MPART = OFF_FEATS + (size_t)S_LEN * NTAG * 4;// f32 [64][25]
static constexpr size_t OFF_GOLD  = OFF_MPART + (size_t)64 * 25 * 4;     // f32 [64]
static constexpr size_t WS_NEEDED = OFF_GOLD + 256;

// ---------- helpers ----------
static __device__ __forceinline__ float fexp_(float x){ return __builtin_amdgcn_exp2f(x * L2E); }
static __device__ __forceinline__ float fsig_(float x){ return __builtin_amdgcn_rcpf(1.0f + fexp_(-x)); }
static __device__ __forceinline__ float ftanh_(float x){ return 1.0f - 2.0f*__builtin_amdgcn_rcpf(fexp_(2.0f*x) + 1.0f); }

static __device__ __forceinline__ float lse5(float t0,float t1,float t2,float t3,float t4){
  float m = fmaxf(fmaxf(fmaxf(t0,t1),fmaxf(t2,t3)),t4);
  float s = __builtin_amdgcn_exp2f((t0-m)*L2E) + __builtin_amdgcn_exp2f((t1-m)*L2E)
          + __builtin_amdgcn_exp2f((t2-m)*L2E) + __builtin_amdgcn_exp2f((t3-m)*L2E)
          + __builtin_amdgcn_exp2f((t4-m)*L2E);
  return m + __builtin_amdgcn_logf(s)*LN2;
}

// C[i][j] = LSE_k(cur[i][k] + bv[k][j]); lane layout: lane = i*5+j (lanes 0..24)
static __device__ __forceinline__ float lse_mm(float cur, float bv, int i, int j){
  const float a0=__shfl(cur, i*5+0), a1=__shfl(cur, i*5+1), a2=__shfl(cur, i*5+2),
              a3=__shfl(cur, i*5+3), a4=__shfl(cur, i*5+4);
  const float c0=__shfl(bv, 0+j),  c1=__shfl(bv, 5+j),  c2=__shfl(bv, 10+j),
              c3=__shfl(bv, 15+j), c4=__shfl(bv, 20+j);
  return lse5(a0+c0, a1+c1, a2+c2, a3+c3, a4+c4);
}

// ---------- phase 0: poison-fill hbs with coherent (sc0 sc1) stores ----------
__global__ __launch_bounds__(256) void fill_poison(float* __restrict__ p, int n4){
  const int idx = blockIdx.x*blockDim.x + threadIdx.x;
  const int stride = gridDim.x*blockDim.x;
  f32x4 pv;
  pv.x = __uint_as_float(POIS_U); pv.y = __uint_as_float(POIS_U);
  pv.z = __uint_as_float(POIS_U); pv.w = __uint_as_float(POIS_U);
  for (int i = idx; i < n4; i += stride) {
    float* dst = p + (size_t)i*4;
    asm volatile("global_store_dwordx4 %0, %1, off sc0 sc1" :: "v"(dst), "v"(pv) : "memory");
  }
}

// ---------- phase A: xp[dir][s][2048] = emb[sent[s]] @ w_ih.T + (b_ih+b_hh), stored bf16 ----------
__global__ __launch_bounds__(256) void xp_gemm(
    const int* __restrict__ sentence, const float* __restrict__ emb,
    const float* __restrict__ w_ih_f, const float* __restrict__ b_ih_f, const float* __restrict__ b_hh_f,
    const float* __restrict__ w_ih_b, const float* __restrict__ b_ih_b, const float* __restrict__ b_hh_b,
    __hip_bfloat16* __restrict__ xp)
{
  __shared__ float At[32][132];
  __shared__ float Bt[32][132];
  __shared__ int sent_s[128];

  const int dir = blockIdx.y;
  const int tm = blockIdx.x & 31;
  const int tn = blockIdx.x >> 5;
  const float* __restrict__ wih = dir ? w_ih_b : w_ih_f;
  const float* __restrict__ bi  = dir ? b_ih_b : b_ih_f;
  const float* __restrict__ bh  = dir ? b_hh_b : b_hh_f;

  const int tid = threadIdx.x;
  if (tid < 128) sent_s[tid] = sentence[tm*128 + tid];

  const int ty = tid >> 4, tx = tid & 15;
  const int li = tid >> 1, lh = tid & 1;

  float acc[8][8];
#pragma unroll
  for (int i = 0; i < 8; ++i){
#pragma unroll
    for (int j = 0; j < 8; ++j) acc[i][j] = 0.0f;
  }
  __syncthreads();

  for (int kc0 = 0; kc0 < EDIM; kc0 += 32) {
    const int kw = (EDIM - kc0 < 32) ? (EDIM - kc0) : 32;
    if (kc0 + lh*16 + 16 <= EDIM) {
      const float4* pa = (const float4*)(emb + (size_t)sent_s[li]*EDIM + kc0 + lh*16);
      const float4* pb = (const float4*)(wih + (size_t)(tn*128 + li)*EDIM + kc0 + lh*16);
#pragma unroll
      for (int v = 0; v < 4; ++v) {
        const float4 a = pa[v], b = pb[v];
        const int kk = lh*16 + v*4;
        At[kk+0][li] = a.x; At[kk+1][li] = a.y; At[kk+2][li] = a.z; At[kk+3][li] = a.w;
        Bt[kk+0][li] = b.x; Bt[kk+1][li] = b.y; Bt[kk+2][li] = b.z; Bt[kk+3][li] = b.w;
      }
    } else {
#pragma unroll
      for (int jj = 0; jj < 16; ++jj) {
        const int col = kc0 + lh*16 + jj;
        float av = 0.f, bv = 0.f;
        if (col < EDIM) {
          av = emb[(size_t)sent_s[li]*EDIM + col];
          bv = wih[(size_t)(tn*128 + li)*EDIM + col];
        }
        At[lh*16+jj][li] = av;
        Bt[lh*16+jj][li] = bv;
      }
    }
    __syncthreads();
#pragma unroll 4
    for (int k = 0; k < kw; ++k) {
      const float4 a0 = *(const float4*)&At[k][ty*8];
      const float4 a1 = *(const float4*)&At[k][ty*8+4];
      const float4 b0 = *(const float4*)&Bt[k][tx*8];
      const float4 b1 = *(const float4*)&Bt[k][tx*8+4];
      const float av[8] = {a0.x,a0.y,a0.z,a0.w,a1.x,a1.y,a1.z,a1.w};
      const float bv[8] = {b0.x,b0.y,b0.z,b0.w,b1.x,b1.y,b1.z,b1.w};
#pragma unroll
      for (int i = 0; i < 8; ++i){
#pragma unroll
        for (int j = 0; j < 8; ++j) acc[i][j] = __builtin_fmaf(av[i], bv[j], acc[i][j]);
      }
    }
    __syncthreads();
  }

  const int n0 = tn*128 + tx*8;
  float bias[8];
#pragma unroll
  for (int j = 0; j < 8; ++j) bias[j] = bi[n0+j] + bh[n0+j];

  __hip_bfloat16* __restrict__ xpd = xp + (size_t)dir * S_LEN * G4;
#pragma unroll
  for (int i = 0; i < 8; ++i) {
    const int m = tm*128 + ty*8 + i;
    __hip_bfloat16 __align__(16) tmp[8];
#pragma unroll
    for (int j = 0; j < 8; ++j) tmp[j] = __float2bfloat16(acc[i][j] + bias[j]);
    *(uint4*)(xpd + (size_t)m*G4 + n0) = *(const uint4*)tmp;
  }
}

// ---------- phase B: persistent BiLSTM — R2's EXACT sync protocol, W (bf16) in 128 KB LDS ----------
// 32 wgs (16/dir) x 512 threads (8 waves). Wave w_ owns units gu = wg*32 + w_*4 + (l&3);
// lane l owns h-cols [8l, 8l+8). Per step: all 8 waves dual-dwordx4 sc0sc1 poison-poll the
// f32 2KB h row; 16-row matvec from LDS bf16; R2 acc[16] reduce-scatter; gates; lanes<4
// store their unit's h as a single dword sc0sc1. No barriers in the loop.
// ONLY change vs R2 (9.15 ms, verified): weights come from LDS instead of the per-step
// L2 restream (256 KB/wg/step) the compiler generated in R2.
__global__ __launch_bounds__(512, 1) void lstm_pers(
    const float* __restrict__ w_hh_f, const float* __restrict__ w_hh_b,
    const __hip_bfloat16* __restrict__ xp, float* __restrict__ hbs)
{
  extern __shared__ unsigned int Wl[];   // [128 rows][256 u32] = 128 rows x 512 bf16 = 128 KB

  const int dir = blockIdx.x >> 4;
  const int wg  = blockIdx.x & 15;
  const int tid = threadIdx.x;
  const int w_  = tid >> 6;              // wave 0..7
  const int l   = tid & 63;
  const int u   = l & 3;                 // unit tracked by this lane's gate path
  const int gu  = wg*32 + w_*4 + u;      // global unit index

  const float* __restrict__ whh = dir ? w_hh_b : w_hh_f;
  const __hip_bfloat16* __restrict__ xpd = xp + (size_t)dir * S_LEN * G4;
  float* __restrict__ hbs_d = hbs + (size_t)dir * S_LEN * HDIM;

  // ---- stage W slice to LDS as bf16 (one-time). LDS row R = ww*16 + ul*4 + g
  //      <- whh row g*HDIM + wg*32 + ww*4 + ul (R2's w[16][8] layout, per wave ww).
  {
    const int R = tid >> 2, q = tid & 3;           // R 0..127; q covers f32 cols [q*128, q*128+128)
    const int g = R & 3, ul = (R >> 2) & 3, ww = R >> 4;
    const float* src = whh + (size_t)(g*HDIM + wg*32 + ww*4 + ul)*HDIM + q*128;
    unsigned int* dst = Wl + R*256 + q*64;         // 64 u32 = 128 bf16
#pragma unroll
    for (int k = 0; k < 128; k += 8) {
      const f32x4 f0 = *(const f32x4*)(src + k);
      const f32x4 f1 = *(const f32x4*)(src + k + 4);
      u32x4 pk;
      pk.x = (unsigned int)__builtin_bit_cast(unsigned short, __float2bfloat16(f0.x))
           | ((unsigned int)__builtin_bit_cast(unsigned short, __float2bfloat16(f0.y)) << 16);
      pk.y = (unsigned int)__builtin_bit_cast(unsigned short, __float2bfloat16(f0.z))
           | ((unsigned int)__builtin_bit_cast(unsigned short, __float2bfloat16(f0.w)) << 16);
      pk.z = (unsigned int)__builtin_bit_cast(unsigned short, __float2bfloat16(f1.x))
           | ((unsigned int)__builtin_bit_cast(unsigned short, __float2bfloat16(f1.y)) << 16);
      pk.w = (unsigned int)__builtin_bit_cast(unsigned short, __float2bfloat16(f1.z))
           | ((unsigned int)__builtin_bit_cast(unsigned short, __float2bfloat16(f1.w)) << 16);
      *(u32x4*)(dst + k/2) = pk;
    }
  }
  __syncthreads();

  const unsigned int* wrow = Wl + (size_t)(w_*16)*256 + l*4;  // row r at wrow + r*256; u32x4 = cols [8l,8l+8)

  // gather lane for row r=4u+g sits at lane (u>>1)+2*(u&1)+4*(g>>1)+8*(g&1)  (R2-verified)
  const int f_ = 2*(l&1) + ((l>>1)&1);

  const __hip_bfloat16* xptr = xpd + (size_t)(dir ? (S_LEN-1) : 0) * G4 + gu;
  const ptrdiff_t xstep = dir ? -(ptrdiff_t)G4 : (ptrdiff_t)G4;
  float xn0 = __bfloat162float(xptr[0*HDIM]);
  float xn1 = __bfloat162float(xptr[1*HDIM]);
  float xn2 = __bfloat162float(xptr[2*HDIM]);
  float xn3 = __bfloat162float(xptr[3*HDIM]);

  const float* psrc = hbs_d + l*8;
  float*       pdst = hbs_d + gu;
  float cst = 0.0f;

#pragma clang loop unroll(disable)
  for (int s = 0; s < S_LEN; ++s) {
    float acc[16];
    if (s == 0) {
#pragma unroll
      for (int r = 0; r < 16; ++r) acc[r] = 0.0f;
    } else {
      // 1. R2's exact poll: dual dwordx4 sc0sc1 + vmcnt(0), all 8 waves redundantly
      f32x4 pa, pb;
      const float* sp = psrc + (size_t)(s-1)*HDIM;
      for (int it = 0; it < (1<<18); ++it) {
        asm volatile(
          "global_load_dwordx4 %0, %2, off sc0 sc1\n\t"
          "global_load_dwordx4 %1, %2, off offset:16 sc0 sc1\n\t"
          "s_waitcnt vmcnt(0)"
          : "=&v"(pa), "=&v"(pb) : "v"(sp));
        const int ok = (__float_as_uint(pa.x) != POIS_U) & (__float_as_uint(pa.y) != POIS_U)
                     & (__float_as_uint(pa.z) != POIS_U) & (__float_as_uint(pa.w) != POIS_U)
                     & (__float_as_uint(pb.x) != POIS_U) & (__float_as_uint(pb.y) != POIS_U)
                     & (__float_as_uint(pb.z) != POIS_U) & (__float_as_uint(pb.w) != POIS_U);
        if (__all(ok)) break;
      }
      // 2. matvec: 16 gate rows x 8 cols, W from LDS bf16
      const float h0=pa.x,h1=pa.y,h2=pa.z,h3=pa.w,h4=pb.x,h5=pb.y,h6=pb.z,h7=pb.w;
#pragma unroll
      for (int r = 0; r < 16; ++r) {
        const u32x4 wv4 = *(const u32x4*)(wrow + r*256);
        float a =            __uint_as_float(wv4.x << 16)        * h0;
        a = __builtin_fmaf(__uint_as_float(wv4.x & 0xFFFF0000u), h1, a);
        a = __builtin_fmaf(__uint_as_float(wv4.y << 16),         h2, a);
        a = __builtin_fmaf(__uint_as_float(wv4.y & 0xFFFF0000u), h3, a);
        a = __builtin_fmaf(__uint_as_float(wv4.z << 16),         h4, a);
        a = __builtin_fmaf(__uint_as_float(wv4.z & 0xFFFF0000u), h5, a);
        a = __builtin_fmaf(__uint_as_float(wv4.w << 16),         h6, a);
        a = __builtin_fmaf(__uint_as_float(wv4.w & 0xFFFF0000u), h7, a);
        acc[r] = a;
      }
    }

    // 3. reduce-scatter: 16 row-partials over 64 lanes -> lane holds one row total (R2-verified)
#pragma unroll
    for (int k = 0; k < 4; ++k) {
      const int m = 1 << k;
      const int half = 8 >> k;
      const bool up = (l & m) != 0;
#pragma unroll
      for (int t = 0; t < half; ++t) {
        const float mine = up ? acc[half+t] : acc[t];
        const float send = up ? acc[t] : acc[half+t];
        acc[t] = mine + __shfl_xor(send, m);
      }
    }
    float tot = acc[0];
    tot += __shfl_xor(tot, 16);
    tot += __shfl_xor(tot, 32);

    // 4. gates for unit u = l&3 (all lanes redundant; lanes 0-3 canonical) — R2-verified gather
    const float gi = __shfl(tot, f_ + 0)  + xn0;
    const float gf = __shfl(tot, f_ + 8)  + xn1;
    const float gg = __shfl(tot, f_ + 4)  + xn2;
    const float go = __shfl(tot, f_ + 12) + xn3;
    const float iv = fsig_(gi), fv = fsig_(gf), zv = ftanh_(gg), ov = fsig_(go);
    cst = fv*cst + iv*zv;
    const float hval = ov * ftanh_(cst);
    if (l < 4) {
      float* dp = pdst + (size_t)s*HDIM;
      asm volatile("global_store_dword %0, %1, off sc0 sc1" :: "v"(dp), "v"(hval));
    }
    // 5. prefetch next step's xp slice (off the critical store path)
    if (s+1 < S_LEN) {
      xptr += xstep;
      xn0 = __bfloat162float(xptr[0*HDIM]);
      xn1 = __bfloat162float(xptr[1*HDIM]);
      xn2 = __bfloat162float(xptr[2*HDIM]);
      xn3 = __bfloat162float(xptr[3*HDIM]);
    }
  }
}

// ---------- phase C: feats[s][t] = [hf,hb] . w_tag[t] + b_tag[t] ----------
// forward h_t = hbs[0][t]; backward h_t = hbs[1][S-1-t]   (R2-verified)
__global__ __launch_bounds__(64) void feats_ker(
    const float* __restrict__ hbs, const float* __restrict__ w_tag,
    const float* __restrict__ b_tag, float* __restrict__ feats)
{
  const int row = blockIdx.x;
  const int l = threadIdx.x;
  const float* __restrict__ hf  = hbs + (size_t)row*HDIM;
  const float* __restrict__ hbk = hbs + (size_t)S_LEN*HDIM + (size_t)(S_LEN-1-row)*HDIM;
  float a0=0,a1=0,a2=0,a3=0,a4=0;
#pragma unroll
  for (int i = 0; i < 8; ++i) {
    const int j = l + i*64;
    const float hfv = hf[j];
    const float hbv = hbk[j];
    a0 += hfv*w_tag[0*1024+j] + hbv*w_tag[0*1024+512+j];
    a1 += hfv*w_tag[1*1024+j] + hbv*w_tag[1*1024+512+j];
    a2 += hfv*w_tag[2*1024+j] + hbv*w_tag[2*1024+512+j];
    a3 += hfv*w_tag[3*1024+j] + hbv*w_tag[3*1024+512+j];
    a4 += hfv*w_tag[4*1024+j] + hbv*w_tag[4*1024+512+j];
  }
#pragma unroll
  for (int off = 32; off; off >>= 1) {
    a0 += __shfl_xor(a0, off); a1 += __shfl_xor(a1, off); a2 += __shfl_xor(a2, off);
    a3 += __shfl_xor(a3, off); a4 += __shfl_xor(a4, off);
  }
  if (l == 0) {
    feats[row*NTAG+0] = a0 + b_tag[0];
    feats[row*NTAG+1] = a1 + b_tag[1];
    feats[row*NTAG+2] = a2 + b_tag[2];
    feats[row*NTAG+3] = a3 + b_tag[3];
    feats[row*NTAG+4] = a4 + b_tag[4];
  }
}

// ---------- phase D: CRF log-partition + gold score ----------
__global__ __launch_bounds__(64) void crf_part(
    const float* __restrict__ feats, const float* __restrict__ trans,
    const int* __restrict__ tags, float* __restrict__ Mpart, float* __restrict__ gold_part)
{
  const int blk = blockIdx.x;         // 64 blocks x 64 steps
  const int l = threadIdx.x;
  const int s0 = blk * 64;
  const bool act = (l < 25);
  const int i = act ? (l/5) : 0;
  const int j = act ? (l%5) : 0;
  const float tT = trans[j*NTAG + i]; // M_s[i][j] = trans[j][i] + feats[s][j]
  float cur = tT + feats[(size_t)s0*NTAG + j];
  for (int s = s0+1; s < s0+64; ++s) {
    const float bv = tT + feats[(size_t)s*NTAG + j];
    cur = lse_mm(cur, bv, i, j);
  }
  if (act) Mpart[blk*25 + l] = cur;

  const int s = s0 + l;
  const int tg = tags[s];
  const int pv = (s == 0) ? START_TAG : tags[s-1];
  float gv = trans[tg*NTAG + pv] + feats[(size_t)s*NTAG + tg];
#pragma unroll
  for (int off = 32; off; off >>= 1) gv += __shfl_xor(gv, off);
  if (l == 0) gold_part[blk] = gv;
}

__global__ __launch_bounds__(64) void crf_final(
    const float* __restrict__ Mpart, const float* __restrict__ gold_part,
    const float* __restrict__ trans, const int* __restrict__ tags, float* __restrict__ out)
{
  const int l = threadIdx.x;
  const bool act = (l < 25);
  const int i = act ? (l/5) : 0;
  const int j = act ? (l%5) : 0;
  float cur = Mpart[act ? l : 0];
  for (int b = 1; b < 64; ++b) {
    const float bv = Mpart[b*25 + (act ? l : 0)];
    cur = lse_mm(cur, bv, i, j);
  }
  const float t0 = ((0==START_TAG)?0.f:NEGV) + __shfl(cur, 0*5 + j);
  const float t1 = ((1==START_TAG)?0.f:NEGV) + __shfl(cur, 1*5 + j);
  const float t2 = ((2==START_TAG)?0.f:NEGV) + __shfl(cur, 2*5 + j);
  const float t3 = ((3==START_TAG)?0.f:NEGV) + __shfl(cur, 3*5 + j);
  const float t4 = ((4==START_TAG)?0.f:NEGV) + __shfl(cur, 4*5 + j);
  const float aF = lse5(t0,t1,t2,t3,t4);       // lanes 0..4 hold aF[j=lane]
  const float f0 = __shfl(aF, 0) + trans[STOP_TAG*NTAG + 0];
  const float f1 = __shfl(aF, 1) + trans[STOP_TAG*NTAG + 1];
  const float f2 = __shfl(aF, 2) + trans[STOP_TAG*NTAG + 2];
  const float f3 = __shfl(aF, 3) + trans[STOP_TAG*NTAG + 3];
  const float f4 = __shfl(aF, 4) + trans[STOP_TAG*NTAG + 4];
  const float fwd = lse5(f0,f1,f2,f3,f4);
  float gv = gold_part[l];
#pragma unroll
  for (int off = 32; off; off >>= 1) gv += __shfl_xor(gv, off);
  if (l == 0) out[0] = fwd - (gv + trans[STOP_TAG*NTAG + tags[S_LEN-1]]);
}

// ---------- launcher ----------
extern "C" void kernel_launch(void* const* d_in, const int* in_sizes, int n_in,
                              void* d_out, int out_size, void* d_ws, size_t ws_size,
                              hipStream_t stream) {
  const int*   sentence = (const int*)d_in[0];
  const int*   tags     = (const int*)d_in[1];
  const float* emb      = (const float*)d_in[2];
  const float* w_ih_f   = (const float*)d_in[3];
  const float* w_hh_f   = (const float*)d_in[4];
  const float* b_ih_f   = (const float*)d_in[5];
  const float* b_hh_f   = (const float*)d_in[6];
  const float* w_ih_b   = (const float*)d_in[7];
  const float* w_hh_b   = (const float*)d_in[8];
  const float* b_ih_b   = (const float*)d_in[9];
  const float* b_hh_b   = (const float*)d_in[10];
  const float* w_tag    = (const float*)d_in[11];
  const float* b_tag    = (const float*)d_in[12];
  const float* trans    = (const float*)d_in[13];
  float* out = (float*)d_out;
  char* ws = (char*)d_ws;
  if (ws_size < WS_NEEDED) return;   // clean wrong-answer instead of OOB

  __hip_bfloat16* xp   = (__hip_bfloat16*)(ws + OFF_XP);
  float* hbs           = (float*)(ws + OFF_HBS);
  float* feats         = (float*)(ws + OFF_FEATS);
  float* Mpart         = (float*)(ws + OFF_MPART);
  float* gold_part     = (float*)(ws + OFF_GOLD);

  const int n4 = (2 * S_LEN * HDIM) / 4;
  fill_poison<<<dim3(1024), dim3(256), 0, stream>>>(hbs, n4);
  xp_gemm<<<dim3(512, 2, 1), dim3(256), 0, stream>>>(sentence, emb,
      w_ih_f, b_ih_f, b_hh_f, w_ih_b, b_ih_b, b_hh_b, xp);
  lstm_pers<<<dim3(32), dim3(512), 131072, stream>>>(w_hh_f, w_hh_b, xp, hbs);
  feats_ker<<<dim3(4096), dim3(64), 0, stream>>>(hbs, w_tag, b_tag, feats);
  crf_part<<<dim3(64), dim3(64), 0, stream>>>(feats, trans, tags, Mpart, gold_part);
  crf_final<<<dim3(1), dim3(64), 0, stream>>>(Mpart, gold_part, trans, tags, out);
}